// Round 4
// baseline (599.801 us; speedup 1.0000x reference)
//
#include <hip/hip_runtime.h>
#include <hip/hip_bf16.h>
#include <math.h>

// Problem constants: N=8, L=1024, D=1024, H=16, hd=64, SCALE=0.125
typedef short bf16x8 __attribute__((ext_vector_type(8)));
typedef float f32x4 __attribute__((ext_vector_type(4)));

__device__ __forceinline__ short f2bf(float f) {
  unsigned u = __float_as_uint(f);
  u += 0x7fffu + ((u >> 16) & 1u);          // RNE
  return (short)(u >> 16);
}
__device__ __forceinline__ float bf2f(short h) {
  return __uint_as_float(((unsigned)(unsigned short)h) << 16);
}

typedef __attribute__((address_space(1))) void glob_void;
typedef __attribute__((address_space(3))) void lds_void;
// async global->LDS, 16B per lane; LDS dest = wave-uniform base + lane*16
__device__ __forceinline__ void async16(const void* g, void* l) {
  __builtin_amdgcn_global_load_lds((glob_void*)(uintptr_t)g,
                                   (lds_void*)(unsigned int)(uintptr_t)l,
                                   16, 0, 0);
}

// ---------------- fp32 -> bf16 conversion of x, W_in, W_out ----------------
__global__ void convert3(const float* __restrict__ a, short* __restrict__ ab, int na4,
                         const float* __restrict__ b, short* __restrict__ bb, int nb4,
                         const float* __restrict__ c, short* __restrict__ cb, int nc4) {
  int tid = blockIdx.x * blockDim.x + threadIdx.x;
  int stride = gridDim.x * blockDim.x;
  for (int i = tid; i < na4; i += stride) {
    float4 v = ((const float4*)a)[i];
    ((short4*)ab)[i] = make_short4(f2bf(v.x), f2bf(v.y), f2bf(v.z), f2bf(v.w));
  }
  for (int i = tid; i < nb4; i += stride) {
    float4 v = ((const float4*)b)[i];
    ((short4*)bb)[i] = make_short4(f2bf(v.x), f2bf(v.y), f2bf(v.z), f2bf(v.w));
  }
  for (int i = tid; i < nc4; i += stride) {
    float4 v = ((const float4*)c)[i];
    ((short4*)cb)[i] = make_short4(f2bf(v.x), f2bf(v.y), f2bf(v.z), f2bf(v.w));
  }
}

// ---------------- m97-style B^T GEMM: C[m][n] = sum_k A[m][k]*B[n][k] + bias[n]
__global__ __launch_bounds__(256, 2) void gemm_bt(
    const short* __restrict__ A, const short* __restrict__ B,
    const float* __restrict__ bias, float* __restrict__ Cf, short* __restrict__ Cb,
    int M, int N, int K) {
  __shared__ short As[128 * 64];
  __shared__ short Bs[128 * 64];
  const int tid = threadIdx.x;
  const int lane = tid & 63, wave = tid >> 6;
  const int wm = (wave & 1) * 64, wn = (wave >> 1) * 64;
  const int lrow = lane & 15, lgrp = lane >> 4;
  const int m0 = blockIdx.y * 128, n0 = blockIdx.x * 128;
  f32x4 acc[4][4] = {};

  const int srow = tid >> 3;                         // 0..31
  const int schunk = ((tid & 7) ^ (srow & 7)) * 8;   // swizzled source chunk (elems)
  const short* Ag = A + (size_t)(m0 + srow) * K + schunk;
  const short* Bg = B + (size_t)(n0 + srow) * K + schunk;
  short* Al = As + tid * 8;
  short* Bl = Bs + tid * 8;

  for (int k0 = 0; k0 < K; k0 += 64) {
    __syncthreads();
#pragma unroll
    for (int r = 0; r < 4; ++r) {
      async16(Ag + (size_t)(32 * r) * K + k0, Al + r * 2048);
      async16(Bg + (size_t)(32 * r) * K + k0, Bl + r * 2048);
    }
    __syncthreads();
#pragma unroll
    for (int kk = 0; kk < 2; ++kk) {
      bf16x8 af[4], bfr[4];
#pragma unroll
      for (int i = 0; i < 4; ++i) {
        const int ra = wm + i * 16 + lrow;
        af[i] = *(const bf16x8*)&As[ra * 64 + (((kk * 4 + lgrp) ^ (ra & 7)) * 8)];
        const int rb = wn + i * 16 + lrow;
        bfr[i] = *(const bf16x8*)&Bs[rb * 64 + (((kk * 4 + lgrp) ^ (rb & 7)) * 8)];
      }
#pragma unroll
      for (int i = 0; i < 4; ++i)
#pragma unroll
        for (int j = 0; j < 4; ++j)
          acc[i][j] = __builtin_amdgcn_mfma_f32_16x16x32_bf16(af[i], bfr[j], acc[i][j], 0, 0, 0);
    }
  }
#pragma unroll
  for (int j = 0; j < 4; ++j) {
    const int col = n0 + wn + j * 16 + lrow;
    const float bs = bias[col];
#pragma unroll
    for (int i = 0; i < 4; ++i) {
      const int rb = m0 + wm + i * 16 + lgrp * 4;
#pragma unroll
      for (int r = 0; r < 4; ++r) {
        const float v = acc[i][j][r] + bs;
        if (Cf) Cf[(size_t)(rb + r) * N + col] = v;
        else    Cb[(size_t)(rb + r) * N + col] = f2bf(v);
      }
    }
  }
}

// ---------------- RoPE + head-split + V transpose ----------------
__global__ __launch_bounds__(256) void rope_kernel(
    const short* __restrict__ qkv, short* __restrict__ qh,
    short* __restrict__ kh, short* __restrict__ vt) {
  __shared__ short vtile[64 * 65];
  const int l0 = blockIdx.x * 64, h = blockIdx.y, n = blockIdx.z;
  const int tid = threadIdx.x;
  const int d = tid & 63, lo = tid >> 6;
  const int j = d & 31;
  const float invf = exp2f(-0.4152410118609203f * (float)j);  // 10000^(-j/32)
  const float sgn = (d < 32) ? -1.0f : 1.0f;
  const int po = ((d + 32) & 63) - d;  // pair offset for rotate_half
  const size_t hb = (size_t)(n * 16 + h) * 1024;
#pragma unroll
  for (int i = 0; i < 16; ++i) {
    const int l = l0 + lo + i * 4;
    const short* row = qkv + (size_t)(n * 1024 + l) * 3072 + h * 64;
    const float qv = bf2f(row[d]),        qp = bf2f(row[d + po]);
    const float kv = bf2f(row[1024 + d]), kp = bf2f(row[1024 + d + po]);
    const float vv = bf2f(row[2048 + d]);
    float s, c;
    sincosf((float)l * invf, &s, &c);
    qh[(hb + l) * 64 + d] = f2bf((qv * c + sgn * qp * s) * 0.125f);
    kh[(hb + l) * 64 + d] = f2bf(kv * c + sgn * kp * s);
    vtile[d * 65 + lo + i * 4] = f2bf(vv);
  }
  __syncthreads();
#pragma unroll
  for (int i = 0; i < 16; ++i) {
    const int dd = lo + i * 4;
    vt[hb * 64 + (size_t)dd * 1024 + l0 + d] = vtile[dd * 65 + d];
  }
}

// ---------------- fused attention, producer/consumer specialized ------------
// block = (n, 16 q-rows), 512 threads / 8 waves, loops all 16 heads.
// Waves 0-3 (PRODUCERS): QK^T with SWAPPED operands mfma(K,Q) so each lane
//   holds P[q=lrow][256-key strip] -> row-sum is lane-local (+2 shfl across
//   lgrp), P-store packs 4 keys into one ds_write_b64. Unnormalized exp goes
//   to a double-buffered 32KB swizzled LDS tile; per-wave sums to ssum[buf].
//   Head-mean macc (16 x f32x4) normalized one iter later, written as out2.
// Waves 4-7 (CONSUMERS): each owns a 16-d output tile over FULL K=1024 (no
//   cross-wave pvred reduce). 32 V loads (L2-hot) + 32 swizzled ds_read_b128,
//   2 independent MFMA chains, scale by inv(h), store attn.
// ONE barrier per head (R3 had 3): QK(h+1) overlaps PV(h). R3's 46k cycles/
// head was pure barrier-phase convoy (3.7% HBM, 4.5% Mfma, traffic at
// compulsory minimum) -- this attacks exactly that.
__global__ __launch_bounds__(512, 2) void attn_fused(
    const short* __restrict__ qh, const short* __restrict__ kh,
    const short* __restrict__ vt, short* __restrict__ attn,
    float* __restrict__ out2) {
  __shared__ short Pl[2][16 * 1024];    // P (unnormalized exp), chunk^(q&7) swizzle
  __shared__ float ssum[2][4][16];      // per-producer-wave row sums
  const int bid = blockIdx.x;
  const int n = bid & 7;                // XCD swizzle: same n -> same XCD L2
  const int q0 = (bid >> 3) * 16;
  const int tid = threadIdx.x;
  const int wave = tid >> 6, lane = tid & 63;
  const int lrow = lane & 15, lgrp = lane >> 4;
  const size_t nb = (size_t)n * 16 * 65536;   // head-0 base for this n

  if (wave < 4) {
    // ================= PRODUCER =================
    const int c0 = wave * 256;          // this wave's 256-key strip
    const f32x4 zero = {};
    f32x4 sacc[16];                     // P[q=lrow][key strip] after exp
    f32x4 macc[16];                     // head-mean accumulator (out2)
#pragma unroll
    for (int nt = 0; nt < 16; ++nt) macc[nt] = zero;

    auto qk_head = [&](int hh, int buf) {
      const size_t hb = nb + (size_t)hh * 65536;
      const short* qb = qh + hb + (size_t)q0 * 64;
      const short* kb = kh + hb;
#pragma unroll
      for (int nt = 0; nt < 16; ++nt) sacc[nt] = zero;
#pragma unroll
      for (int kk = 0; kk < 2; ++kk) {
        const bf16x8 bq = *(const bf16x8*)(qb + lrow * 64 + kk * 32 + lgrp * 8);
#pragma unroll
        for (int nt = 0; nt < 16; ++nt) {
          const int key = c0 + nt * 16 + lrow;
          const bf16x8 ak = *(const bf16x8*)(kb + (size_t)key * 64 + kk * 32 + lgrp * 8);
          // swapped: D[key_local][q] -> lane holds q=lrow, keys lgrp*4+r
          sacc[nt] = __builtin_amdgcn_mfma_f32_16x16x32_bf16(ak, bq, sacc[nt], 0, 0, 0);
        }
      }
      // exp + lane-local row sum (all 64 values belong to q-row lrow)
      float rs = 0.f;
#pragma unroll
      for (int nt = 0; nt < 16; ++nt)
#pragma unroll
        for (int r = 0; r < 4; ++r) {
          const float e = __expf(sacc[nt][r]);
          sacc[nt][r] = e;
          rs += e;
        }
      rs += __shfl_xor(rs, 16, 64);     // sum across lgrp (keys mod 16)
      rs += __shfl_xor(rs, 32, 64);
      if (lgrp == 0) ssum[buf][wave][lrow] = rs;
      // P store: row q=lrow, 4 consecutive keys per ds_write_b64
#pragma unroll
      for (int nt = 0; nt < 16; ++nt) {
        short4 pk;
        pk.x = f2bf(sacc[nt][0]); pk.y = f2bf(sacc[nt][1]);
        pk.z = f2bf(sacc[nt][2]); pk.w = f2bf(sacc[nt][3]);
        const int col = c0 + nt * 16 + lgrp * 4;
        const int chunk = col >> 3, wi = col & 7;
        *(short4*)&Pl[buf][lrow * 1024 + ((chunk ^ (lrow & 7)) << 3) + wi] = pk;
      }
    };

    qk_head(0, 0);
    __syncthreads();
    for (int h = 0; h < 16; ++h) {
      const int cur = h & 1;
      // macc for head h (sacc still holds exp(S(h)); inv(h) now visible)
      const float s = ssum[cur][0][lrow] + ssum[cur][1][lrow] +
                      ssum[cur][2][lrow] + ssum[cur][3][lrow];
      const float inv = 1.0f / s;
#pragma unroll
      for (int nt = 0; nt < 16; ++nt)
#pragma unroll
        for (int r = 0; r < 4; ++r) macc[nt][r] += sacc[nt][r] * inv;
      if (h < 15) qk_head(h + 1, cur ^ 1);
      __syncthreads();
    }
    // out2 = mean over 16 heads; row q=lrow, coalesced dwordx4 per nt
#pragma unroll
    for (int nt = 0; nt < 16; ++nt) {
      f32x4 o = macc[nt] * 0.0625f;
      const int col = c0 + nt * 16 + lgrp * 4;
      *(f32x4*)&out2[(size_t)(n * 1024 + q0 + lrow) * 1024 + col] = o;
    }
  } else {
    // ================= CONSUMER =================
    const int dstrip = wave - 4;        // d cols [dstrip*16, +16)
    const short* vbase = vt + nb + (size_t)(dstrip * 16 + lrow) * 1024;
    __syncthreads();                    // matches producer prologue barrier
    for (int h = 0; h < 16; ++h) {
      const int cur = h & 1;
      float inv4[4];
#pragma unroll
      for (int r = 0; r < 4; ++r) {
        const int row = lgrp * 4 + r;
        inv4[r] = 1.0f / (ssum[cur][0][row] + ssum[cur][1][row] +
                          ssum[cur][2][row] + ssum[cur][3][row]);
      }
      const short* vb = vbase + (size_t)h * 65536;
      f32x4 pva = {}, pvb = {};         // two chains halve serial MFMA latency
#pragma unroll
      for (int kk = 0; kk < 32; kk += 2) {
        const bf16x8 pa0 = *(const bf16x8*)&Pl[cur][lrow * 1024 +
              (((kk * 4 + lgrp) ^ (lrow & 7)) << 3)];
        const bf16x8 vf0 = *(const bf16x8*)(vb + kk * 32 + lgrp * 8);
        pva = __builtin_amdgcn_mfma_f32_16x16x32_bf16(pa0, vf0, pva, 0, 0, 0);
        const bf16x8 pa1 = *(const bf16x8*)&Pl[cur][lrow * 1024 +
              ((((kk + 1) * 4 + lgrp) ^ (lrow & 7)) << 3)];
        const bf16x8 vf1 = *(const bf16x8*)(vb + (kk + 1) * 32 + lgrp * 8);
        pvb = __builtin_amdgcn_mfma_f32_16x16x32_bf16(pa1, vf1, pvb, 0, 0, 0);
      }
#pragma unroll
      for (int r = 0; r < 4; ++r) {
        const float v = (pva[r] + pvb[r]) * inv4[r];
        attn[(size_t)(n * 1024 + q0 + lgrp * 4 + r) * 1024 +
             h * 64 + dstrip * 16 + lrow] = f2bf(v);
      }
      __syncthreads();
    }
  }
}

extern "C" void kernel_launch(void* const* d_in, const int* in_sizes, int n_in,
                              void* d_out, int out_size, void* d_ws, size_t ws_size,
                              hipStream_t stream) {
  const float* x  = (const float*)d_in[0];   // (8,1024,1024)
  const float* Wi = (const float*)d_in[1];   // (3072,1024)
  const float* bi = (const float*)d_in[2];   // (3072,)
  const float* Wo = (const float*)d_in[3];   // (1024,1024)
  const float* bo = (const float*)d_in[4];   // (1024,)
  float* out  = (float*)d_out;                       // (8,1024,1024)
  float* out2 = out + (size_t)8 * 1024 * 1024;       // (8,1024,1024) mean attn

  char* p = (char*)d_ws;
  short* xb  = (short*)p; p += (size_t)8388608 * 2;   // x bf16 (reused as attn later)
  short* wb  = (short*)p; p += (size_t)3145728 * 2;   // W_in bf16
  short* wob = (short*)p; p += (size_t)1048576 * 2;   // W_out bf16
  short* qkv = (short*)p; p += (size_t)8 * 1024 * 3072 * 2;  // 50.3 MB (dead after rope)
  short* qh  = (short*)p; p += (size_t)8388608 * 2;   // (n,h,l,d) bf16, pre-scaled
  short* kh  = (short*)p; p += (size_t)8388608 * 2;   // (n,h,l,d) bf16
  short* vt  = (short*)p; p += (size_t)8388608 * 2;   // (n,h,d,l) bf16
  short* attn = xb;  // xb dead after gemm_qkv

  convert3<<<2048, 256, 0, stream>>>(x, xb, 8388608 / 4, Wi, wb, 3145728 / 4,
                                     Wo, wob, 1048576 / 4);
  gemm_bt<<<dim3(24, 64), 256, 0, stream>>>(xb, wb, bi, nullptr, qkv, 8192, 3072, 1024);
  rope_kernel<<<dim3(16, 16, 8), 256, 0, stream>>>(qkv, qh, kh, vt);
  attn_fused<<<512, 512, 0, stream>>>(qh, kh, vt, attn, out2);
  gemm_bt<<<dim3(8, 64), 256, 0, stream>>>(attn, wob, bo, out, nullptr, 8192, 1024, 1024);
}

// Round 5
// 323.489 us; speedup vs baseline: 1.8542x; 1.8542x over previous
//
#include <hip/hip_runtime.h>
#include <hip/hip_bf16.h>
#include <math.h>

// Problem constants: N=8, L=1024, D=1024, H=16, hd=64, SCALE=0.125
typedef short bf16x8 __attribute__((ext_vector_type(8)));
typedef float f32x4 __attribute__((ext_vector_type(4)));

__device__ __forceinline__ short f2bf(float f) {
  unsigned u = __float_as_uint(f);
  u += 0x7fffu + ((u >> 16) & 1u);          // RNE
  return (short)(u >> 16);
}
__device__ __forceinline__ float bf2f(short h) {
  return __uint_as_float(((unsigned)(unsigned short)h) << 16);
}

typedef __attribute__((address_space(1))) void glob_void;
typedef __attribute__((address_space(3))) void lds_void;
// async global->LDS, 16B per lane; LDS dest = wave-uniform base + lane*16
__device__ __forceinline__ void async16(const void* g, void* l) {
  __builtin_amdgcn_global_load_lds((glob_void*)(uintptr_t)g,
                                   (lds_void*)(unsigned int)(uintptr_t)l,
                                   16, 0, 0);
}

// ---------------- fp32 -> bf16 conversion of x, W_in, W_out ----------------
__global__ void convert3(const float* __restrict__ a, short* __restrict__ ab, int na4,
                         const float* __restrict__ b, short* __restrict__ bb, int nb4,
                         const float* __restrict__ c, short* __restrict__ cb, int nc4) {
  int tid = blockIdx.x * blockDim.x + threadIdx.x;
  int stride = gridDim.x * blockDim.x;
  for (int i = tid; i < na4; i += stride) {
    float4 v = ((const float4*)a)[i];
    ((short4*)ab)[i] = make_short4(f2bf(v.x), f2bf(v.y), f2bf(v.z), f2bf(v.w));
  }
  for (int i = tid; i < nb4; i += stride) {
    float4 v = ((const float4*)b)[i];
    ((short4*)bb)[i] = make_short4(f2bf(v.x), f2bf(v.y), f2bf(v.z), f2bf(v.w));
  }
  for (int i = tid; i < nc4; i += stride) {
    float4 v = ((const float4*)c)[i];
    ((short4*)cb)[i] = make_short4(f2bf(v.x), f2bf(v.y), f2bf(v.z), f2bf(v.w));
  }
}

// ---------------- m97-style B^T GEMM: C[m][n] = sum_k A[m][k]*B[n][k] + bias[n]
__global__ __launch_bounds__(256, 2) void gemm_bt(
    const short* __restrict__ A, const short* __restrict__ B,
    const float* __restrict__ bias, float* __restrict__ Cf, short* __restrict__ Cb,
    int M, int N, int K) {
  __shared__ short As[128 * 64];
  __shared__ short Bs[128 * 64];
  const int tid = threadIdx.x;
  const int lane = tid & 63, wave = tid >> 6;
  const int wm = (wave & 1) * 64, wn = (wave >> 1) * 64;
  const int lrow = lane & 15, lgrp = lane >> 4;
  const int m0 = blockIdx.y * 128, n0 = blockIdx.x * 128;
  f32x4 acc[4][4] = {};

  const int srow = tid >> 3;                         // 0..31
  const int schunk = ((tid & 7) ^ (srow & 7)) * 8;   // swizzled source chunk (elems)
  const short* Ag = A + (size_t)(m0 + srow) * K + schunk;
  const short* Bg = B + (size_t)(n0 + srow) * K + schunk;
  short* Al = As + tid * 8;
  short* Bl = Bs + tid * 8;

  for (int k0 = 0; k0 < K; k0 += 64) {
    __syncthreads();
#pragma unroll
    for (int r = 0; r < 4; ++r) {
      async16(Ag + (size_t)(32 * r) * K + k0, Al + r * 2048);
      async16(Bg + (size_t)(32 * r) * K + k0, Bl + r * 2048);
    }
    __syncthreads();
#pragma unroll
    for (int kk = 0; kk < 2; ++kk) {
      bf16x8 af[4], bfr[4];
#pragma unroll
      for (int i = 0; i < 4; ++i) {
        const int ra = wm + i * 16 + lrow;
        af[i] = *(const bf16x8*)&As[ra * 64 + (((kk * 4 + lgrp) ^ (ra & 7)) * 8)];
        const int rb = wn + i * 16 + lrow;
        bfr[i] = *(const bf16x8*)&Bs[rb * 64 + (((kk * 4 + lgrp) ^ (rb & 7)) * 8)];
      }
#pragma unroll
      for (int i = 0; i < 4; ++i)
#pragma unroll
        for (int j = 0; j < 4; ++j)
          acc[i][j] = __builtin_amdgcn_mfma_f32_16x16x32_bf16(af[i], bfr[j], acc[i][j], 0, 0, 0);
    }
  }
#pragma unroll
  for (int j = 0; j < 4; ++j) {
    const int col = n0 + wn + j * 16 + lrow;
    const float bs = bias[col];
#pragma unroll
    for (int i = 0; i < 4; ++i) {
      const int rb = m0 + wm + i * 16 + lgrp * 4;
#pragma unroll
      for (int r = 0; r < 4; ++r) {
        const float v = acc[i][j][r] + bs;
        if (Cf) Cf[(size_t)(rb + r) * N + col] = v;
        else    Cb[(size_t)(rb + r) * N + col] = f2bf(v);
      }
    }
  }
}

// ---------------- RoPE + head-split + V transpose ----------------
__global__ __launch_bounds__(256) void rope_kernel(
    const short* __restrict__ qkv, short* __restrict__ qh,
    short* __restrict__ kh, short* __restrict__ vt) {
  __shared__ short vtile[64 * 65];
  const int l0 = blockIdx.x * 64, h = blockIdx.y, n = blockIdx.z;
  const int tid = threadIdx.x;
  const int d = tid & 63, lo = tid >> 6;
  const int j = d & 31;
  const float invf = exp2f(-0.4152410118609203f * (float)j);  // 10000^(-j/32)
  const float sgn = (d < 32) ? -1.0f : 1.0f;
  const int po = ((d + 32) & 63) - d;  // pair offset for rotate_half
  const size_t hb = (size_t)(n * 16 + h) * 1024;
#pragma unroll
  for (int i = 0; i < 16; ++i) {
    const int l = l0 + lo + i * 4;
    const short* row = qkv + (size_t)(n * 1024 + l) * 3072 + h * 64;
    const float qv = bf2f(row[d]),        qp = bf2f(row[d + po]);
    const float kv = bf2f(row[1024 + d]), kp = bf2f(row[1024 + d + po]);
    const float vv = bf2f(row[2048 + d]);
    float s, c;
    sincosf((float)l * invf, &s, &c);
    qh[(hb + l) * 64 + d] = f2bf((qv * c + sgn * qp * s) * 0.125f);
    kh[(hb + l) * 64 + d] = f2bf(kv * c + sgn * kp * s);
    vtile[d * 65 + lo + i * 4] = f2bf(vv);
  }
  __syncthreads();
#pragma unroll
  for (int i = 0; i < 16; ++i) {
    const int dd = lo + i * 4;
    vt[hb * 64 + (size_t)dd * 1024 + l0 + d] = vtile[dd * 65 + d];
  }
}

// ---------------- flash attention: attn + inv-denominators ------------------
// block = (n, h, 128 q-rows), 256 thr / 4 waves; wave owns 32 q-rows end-to-end
// (NO cross-wave softmax coupling). gemm_bt-style kv-loop, 64 keys/step:
//   stage K[64x64]+V^T[64x64] via async16 (proven swizzle pair), S = Q@K^T
//   (Q-frags in regs), exp -> per-wave PRIVATE LDS P tile (write C-layout,
//   read back A-frags; same-wave -> no barrier, lgkmcnt only), PV from
//   LDS P x LDS V^T into O regs. Row-sums accumulate per-lane (C-layout rows
//   are lane-local), one shfl-reduce after the loop, O *= inv, store attn +
//   inv to denw for out2_kernel. R0/R3/R4 were ~90% stall (register-loaded
//   global MFMA operands); this reuses gemm_bt's LDS-operand structure.
__global__ __launch_bounds__(256, 2) void flash_attn(
    const short* __restrict__ qh, const short* __restrict__ kh,
    const short* __restrict__ vt, short* __restrict__ attn,
    float* __restrict__ denw) {
  __shared__ short Ks[64 * 64];
  __shared__ short Vs[64 * 64];
  __shared__ short Pl[4][32 * 64];      // per-wave private P tiles
  const int bid = blockIdx.x;
  const int n = bid & 7;                // same n -> same XCD (L2 locality)
  const int h = (bid >> 3) & 15;
  const int q0 = (bid >> 7) * 128;
  const int tid = threadIdx.x;
  const int wave = tid >> 6, lane = tid & 63;
  const int lrow = lane & 15, lgrp = lane >> 4;
  const int woff = wave * 32;
  const size_t hb = (size_t)(n * 16 + h) * 65536;

  // Q fragments, held in regs for the whole kernel (rows = q, k-dim = d)
  bf16x8 aq[2][2];
#pragma unroll
  for (int i = 0; i < 2; ++i)
#pragma unroll
    for (int kk = 0; kk < 2; ++kk)
      aq[i][kk] = *(const bf16x8*)(qh + hb +
          (size_t)(q0 + woff + 16 * i + lrow) * 64 + kk * 32 + lgrp * 8);

  const int srow = tid >> 3;                         // 0..31
  const int schunk = ((tid & 7) ^ (srow & 7)) * 8;   // swizzled source chunk
  const short* Kg = kh + hb + (size_t)srow * 64 + schunk;
  const short* Vg = vt + hb + (size_t)srow * 1024 + schunk;
  short* Kl = Ks + tid * 8;
  short* Vl = Vs + tid * 8;
  short* Pw = &Pl[wave][0];             // this wave's 32x64 tile

  f32x4 osum[2][4] = {};
  float rsum[8] = {0.f, 0.f, 0.f, 0.f, 0.f, 0.f, 0.f, 0.f};

  for (int k0 = 0; k0 < 1024; k0 += 64) {
    __syncthreads();
#pragma unroll
    for (int r = 0; r < 2; ++r) {
      async16(Kg + (size_t)(k0 + 32 * r) * 64, Kl + r * 2048);
      async16(Vg + (size_t)(32 * r) * 1024 + k0, Vl + r * 2048);
    }
    __syncthreads();
    // ---- S = Q @ K^T for this wave's 32 q-rows x 64 keys ----
    f32x4 sacc[2][4] = {};
#pragma unroll
    for (int kk = 0; kk < 2; ++kk)
#pragma unroll
      for (int nt = 0; nt < 4; ++nt) {
        const int rb = nt * 16 + lrow;
        const bf16x8 bk = *(const bf16x8*)&Ks[rb * 64 + (((kk * 4 + lgrp) ^ (rb & 7)) * 8)];
#pragma unroll
        for (int i = 0; i < 2; ++i)
          sacc[i][nt] = __builtin_amdgcn_mfma_f32_16x16x32_bf16(aq[i][kk], bk, sacc[i][nt], 0, 0, 0);
      }
    // ---- exp, rowsum accumulate, P -> private LDS (swizzled) ----
#pragma unroll
    for (int i = 0; i < 2; ++i)
#pragma unroll
      for (int nt = 0; nt < 4; ++nt)
#pragma unroll
        for (int r = 0; r < 4; ++r) {
          const float e = __expf(sacc[i][nt][r]);
          rsum[i * 4 + r] += e;
          const int row = 16 * i + lgrp * 4 + r;
          const int col = 16 * nt + lrow;
          Pw[row * 64 + (((col >> 3) ^ (row & 7)) << 3) + (col & 7)] = f2bf(e);
        }
    // ---- PV: O += P @ V (V^T rows = d) ----
#pragma unroll
    for (int kk = 0; kk < 2; ++kk) {
      bf16x8 pa[2], bv[4];
#pragma unroll
      for (int i = 0; i < 2; ++i) {
        const int ra = 16 * i + lrow;
        pa[i] = *(const bf16x8*)&Pw[ra * 64 + (((kk * 4 + lgrp) ^ (ra & 7)) * 8)];
      }
#pragma unroll
      for (int j = 0; j < 4; ++j) {
        const int rb = 16 * j + lrow;
        bv[j] = *(const bf16x8*)&Vs[rb * 64 + (((kk * 4 + lgrp) ^ (rb & 7)) * 8)];
      }
#pragma unroll
      for (int i = 0; i < 2; ++i)
#pragma unroll
        for (int j = 0; j < 4; ++j)
          osum[i][j] = __builtin_amdgcn_mfma_f32_16x16x32_bf16(pa[i], bv[j], osum[i][j], 0, 0, 0);
    }
  }
  // ---- rowsum reduce across the 16 lrow lanes; normalize; store ----
#pragma unroll
  for (int off = 1; off < 16; off <<= 1)
#pragma unroll
    for (int t = 0; t < 8; ++t) rsum[t] += __shfl_xor(rsum[t], off, 64);
  float inv[8];
#pragma unroll
  for (int t = 0; t < 8; ++t) inv[t] = 1.0f / rsum[t];
  if (lrow == 0) {
#pragma unroll
    for (int i = 0; i < 2; ++i)
#pragma unroll
      for (int r = 0; r < 4; ++r)
        denw[(size_t)(n * 16 + h) * 1024 + q0 + woff + 16 * i + lgrp * 4 + r] = inv[i * 4 + r];
  }
#pragma unroll
  for (int i = 0; i < 2; ++i)
#pragma unroll
    for (int j = 0; j < 4; ++j)
#pragma unroll
      for (int r = 0; r < 4; ++r) {
        const int row = q0 + woff + 16 * i + lgrp * 4 + r;
        attn[(size_t)(n * 1024 + row) * 1024 + h * 64 + 16 * j + lrow] =
            f2bf(osum[i][j][r] * inv[i * 4 + r]);
      }
}

// ---------------- out2 = mean over heads of softmax(S) ----------------------
// block = (n, 128 q-rows, 64-key strip), 256 thr / 4 waves; wave owns 32 q.
// Recomputes QK^T per head (FLOPs cheap), multiplies exp by precomputed inv
// from flash_attn's denw, accumulates the q x k tile over all 16 heads in
// regs, writes out2 exactly once (coalesced). K staged via async16; 2
// barriers/head; no softmax reductions at all.
__global__ __launch_bounds__(256, 2) void out2_kernel(
    const short* __restrict__ qh, const short* __restrict__ kh,
    const float* __restrict__ denw, float* __restrict__ out2) {
  __shared__ short Ks[64 * 64];
  const int bid = blockIdx.x;
  const int n = bid & 7;
  const int qt = (bid >> 3) & 7;
  const int kvs = bid >> 6;             // 0..15
  const int q0 = qt * 128, c0 = kvs * 64;
  const int tid = threadIdx.x;
  const int wave = tid >> 6, lane = tid & 63;
  const int lrow = lane & 15, lgrp = lane >> 4;
  const int woff = wave * 32;

  const int srow = tid >> 3;
  const int schunk = ((tid & 7) ^ (srow & 7)) * 8;
  short* Kl = Ks + tid * 8;

  f32x4 acc[2][4] = {};

  for (int h = 0; h < 16; ++h) {
    const size_t hb = (size_t)(n * 16 + h) * 65536;
    __syncthreads();
#pragma unroll
    for (int r = 0; r < 2; ++r)
      async16(kh + hb + (size_t)(c0 + 32 * r + srow) * 64 + schunk, Kl + r * 2048);
    __syncthreads();
    bf16x8 aq[2][2];
#pragma unroll
    for (int i = 0; i < 2; ++i)
#pragma unroll
      for (int kk = 0; kk < 2; ++kk)
        aq[i][kk] = *(const bf16x8*)(qh + hb +
            (size_t)(q0 + woff + 16 * i + lrow) * 64 + kk * 32 + lgrp * 8);
    f32x4 sacc[2][4] = {};
#pragma unroll
    for (int kk = 0; kk < 2; ++kk)
#pragma unroll
      for (int nt = 0; nt < 4; ++nt) {
        const int rb = nt * 16 + lrow;
        const bf16x8 bk = *(const bf16x8*)&Ks[rb * 64 + (((kk * 4 + lgrp) ^ (rb & 7)) * 8)];
#pragma unroll
        for (int i = 0; i < 2; ++i)
          sacc[i][nt] = __builtin_amdgcn_mfma_f32_16x16x32_bf16(aq[i][kk], bk, sacc[i][nt], 0, 0, 0);
      }
    float invv[8];
#pragma unroll
    for (int i = 0; i < 2; ++i)
#pragma unroll
      for (int r = 0; r < 4; ++r)
        invv[i * 4 + r] = denw[(size_t)(n * 16 + h) * 1024 + q0 + woff + 16 * i + lgrp * 4 + r];
#pragma unroll
    for (int i = 0; i < 2; ++i)
#pragma unroll
      for (int nt = 0; nt < 4; ++nt)
#pragma unroll
        for (int r = 0; r < 4; ++r)
          acc[i][nt][r] += __expf(sacc[i][nt][r]) * invv[i * 4 + r];
  }
#pragma unroll
  for (int i = 0; i < 2; ++i)
#pragma unroll
    for (int nt = 0; nt < 4; ++nt)
#pragma unroll
      for (int r = 0; r < 4; ++r) {
        const int row = q0 + woff + 16 * i + lgrp * 4 + r;
        out2[(size_t)(n * 1024 + row) * 1024 + c0 + 16 * nt + lrow] = acc[i][nt][r] * 0.0625f;
      }
}

extern "C" void kernel_launch(void* const* d_in, const int* in_sizes, int n_in,
                              void* d_out, int out_size, void* d_ws, size_t ws_size,
                              hipStream_t stream) {
  const float* x  = (const float*)d_in[0];   // (8,1024,1024)
  const float* Wi = (const float*)d_in[1];   // (3072,1024)
  const float* bi = (const float*)d_in[2];   // (3072,)
  const float* Wo = (const float*)d_in[3];   // (1024,1024)
  const float* bo = (const float*)d_in[4];   // (1024,)
  float* out  = (float*)d_out;                       // (8,1024,1024)
  float* out2 = out + (size_t)8 * 1024 * 1024;       // (8,1024,1024) mean attn

  char* p = (char*)d_ws;
  short* xb  = (short*)p; p += (size_t)8388608 * 2;   // x bf16 (reused as attn later)
  short* wb  = (short*)p; p += (size_t)3145728 * 2;   // W_in bf16
  short* wob = (short*)p; p += (size_t)1048576 * 2;   // W_out bf16
  short* qkv = (short*)p; p += (size_t)8 * 1024 * 3072 * 2;  // 50.3 MB (dead after rope)
  short* qh  = (short*)p; p += (size_t)8388608 * 2;   // (n,h,l,d) bf16, pre-scaled
  short* kh  = (short*)p; p += (size_t)8388608 * 2;   // (n,h,l,d) bf16
  short* vt  = (short*)p; p += (size_t)8388608 * 2;   // (n,h,d,l) bf16
  float* denw = (float*)p; p += (size_t)131072 * 4;   // inv softmax denominators
  short* attn = xb;  // xb dead after gemm_qkv

  convert3<<<2048, 256, 0, stream>>>(x, xb, 8388608 / 4, Wi, wb, 3145728 / 4,
                                     Wo, wob, 1048576 / 4);
  gemm_bt<<<dim3(24, 64), 256, 0, stream>>>(xb, wb, bi, nullptr, qkv, 8192, 3072, 1024);
  rope_kernel<<<dim3(16, 16, 8), 256, 0, stream>>>(qkv, qh, kh, vt);
  flash_attn<<<1024, 256, 0, stream>>>(qh, kh, vt, attn, denw);
  out2_kernel<<<1024, 256, 0, stream>>>(qh, kh, denw, out2);
  gemm_bt<<<dim3(8, 64), 256, 0, stream>>>(attn, wob, bo, out, nullptr, 8192, 1024, 1024);
}

// Round 6
// 289.899 us; speedup vs baseline: 2.0690x; 1.1159x over previous
//
#include <hip/hip_runtime.h>
#include <hip/hip_bf16.h>
#include <math.h>

// Problem constants: N=8, L=1024, D=1024, H=16, hd=64, SCALE=0.125
typedef short bf16x8 __attribute__((ext_vector_type(8)));
typedef float f32x4 __attribute__((ext_vector_type(4)));

__device__ __forceinline__ short f2bf(float f) {
  unsigned u = __float_as_uint(f);
  u += 0x7fffu + ((u >> 16) & 1u);          // RNE
  return (short)(u >> 16);
}
__device__ __forceinline__ float bf2f(short h) {
  return __uint_as_float(((unsigned)(unsigned short)h) << 16);
}

typedef __attribute__((address_space(1))) void glob_void;
typedef __attribute__((address_space(3))) void lds_void;
// async global->LDS, 16B per lane; LDS dest = wave-uniform base + lane*16
__device__ __forceinline__ void async16(const void* g, void* l) {
  __builtin_amdgcn_global_load_lds((glob_void*)(uintptr_t)g,
                                   (lds_void*)(unsigned int)(uintptr_t)l,
                                   16, 0, 0);
}

// ---------------- fp32 -> bf16 conversion of x, W_in, W_out ----------------
__global__ void convert3(const float* __restrict__ a, short* __restrict__ ab, int na4,
                         const float* __restrict__ b, short* __restrict__ bb, int nb4,
                         const float* __restrict__ c, short* __restrict__ cb, int nc4) {
  int tid = blockIdx.x * blockDim.x + threadIdx.x;
  int stride = gridDim.x * blockDim.x;
  for (int i = tid; i < na4; i += stride) {
    float4 v = ((const float4*)a)[i];
    ((short4*)ab)[i] = make_short4(f2bf(v.x), f2bf(v.y), f2bf(v.z), f2bf(v.w));
  }
  for (int i = tid; i < nb4; i += stride) {
    float4 v = ((const float4*)b)[i];
    ((short4*)bb)[i] = make_short4(f2bf(v.x), f2bf(v.y), f2bf(v.z), f2bf(v.w));
  }
  for (int i = tid; i < nc4; i += stride) {
    float4 v = ((const float4*)c)[i];
    ((short4*)cb)[i] = make_short4(f2bf(v.x), f2bf(v.y), f2bf(v.z), f2bf(v.w));
  }
}

// ---------------- m97-style B^T GEMM: C[m][n] = sum_k A[m][k]*B[n][k] + bias[n]
__global__ __launch_bounds__(256, 2) void gemm_bt(
    const short* __restrict__ A, const short* __restrict__ B,
    const float* __restrict__ bias, float* __restrict__ Cf, short* __restrict__ Cb,
    int M, int N, int K) {
  __shared__ short As[128 * 64];
  __shared__ short Bs[128 * 64];
  const int tid = threadIdx.x;
  const int lane = tid & 63, wave = tid >> 6;
  const int wm = (wave & 1) * 64, wn = (wave >> 1) * 64;
  const int lrow = lane & 15, lgrp = lane >> 4;
  const int m0 = blockIdx.y * 128, n0 = blockIdx.x * 128;
  f32x4 acc[4][4] = {};

  const int srow = tid >> 3;                         // 0..31
  const int schunk = ((tid & 7) ^ (srow & 7)) * 8;   // swizzled source chunk (elems)
  const short* Ag = A + (size_t)(m0 + srow) * K + schunk;
  const short* Bg = B + (size_t)(n0 + srow) * K + schunk;
  short* Al = As + tid * 8;
  short* Bl = Bs + tid * 8;

  for (int k0 = 0; k0 < K; k0 += 64) {
    __syncthreads();
#pragma unroll
    for (int r = 0; r < 4; ++r) {
      async16(Ag + (size_t)(32 * r) * K + k0, Al + r * 2048);
      async16(Bg + (size_t)(32 * r) * K + k0, Bl + r * 2048);
    }
    __syncthreads();
#pragma unroll
    for (int kk = 0; kk < 2; ++kk) {
      bf16x8 af[4], bfr[4];
#pragma unroll
      for (int i = 0; i < 4; ++i) {
        const int ra = wm + i * 16 + lrow;
        af[i] = *(const bf16x8*)&As[ra * 64 + (((kk * 4 + lgrp) ^ (ra & 7)) * 8)];
        const int rb = wn + i * 16 + lrow;
        bfr[i] = *(const bf16x8*)&Bs[rb * 64 + (((kk * 4 + lgrp) ^ (rb & 7)) * 8)];
      }
#pragma unroll
      for (int i = 0; i < 4; ++i)
#pragma unroll
        for (int j = 0; j < 4; ++j)
          acc[i][j] = __builtin_amdgcn_mfma_f32_16x16x32_bf16(af[i], bfr[j], acc[i][j], 0, 0, 0);
    }
  }
#pragma unroll
  for (int j = 0; j < 4; ++j) {
    const int col = n0 + wn + j * 16 + lrow;
    const float bs = bias[col];
#pragma unroll
    for (int i = 0; i < 4; ++i) {
      const int rb = m0 + wm + i * 16 + lgrp * 4;
#pragma unroll
      for (int r = 0; r < 4; ++r) {
        const float v = acc[i][j][r] + bs;
        if (Cf) Cf[(size_t)(rb + r) * N + col] = v;
        else    Cb[(size_t)(rb + r) * N + col] = f2bf(v);
      }
    }
  }
}

// ---------------- RoPE + head-split + V transpose ----------------
__global__ __launch_bounds__(256) void rope_kernel(
    const short* __restrict__ qkv, short* __restrict__ qh,
    short* __restrict__ kh, short* __restrict__ vt) {
  __shared__ short vtile[64 * 65];
  const int l0 = blockIdx.x * 64, h = blockIdx.y, n = blockIdx.z;
  const int tid = threadIdx.x;
  const int d = tid & 63, lo = tid >> 6;
  const int j = d & 31;
  const float invf = exp2f(-0.4152410118609203f * (float)j);  // 10000^(-j/32)
  const float sgn = (d < 32) ? -1.0f : 1.0f;
  const int po = ((d + 32) & 63) - d;  // pair offset for rotate_half
  const size_t hb = (size_t)(n * 16 + h) * 1024;
#pragma unroll
  for (int i = 0; i < 16; ++i) {
    const int l = l0 + lo + i * 4;
    const short* row = qkv + (size_t)(n * 1024 + l) * 3072 + h * 64;
    const float qv = bf2f(row[d]),        qp = bf2f(row[d + po]);
    const float kv = bf2f(row[1024 + d]), kp = bf2f(row[1024 + d + po]);
    const float vv = bf2f(row[2048 + d]);
    float s, c;
    sincosf((float)l * invf, &s, &c);
    qh[(hb + l) * 64 + d] = f2bf((qv * c + sgn * qp * s) * 0.125f);
    kh[(hb + l) * 64 + d] = f2bf(kv * c + sgn * kp * s);
    vtile[d * 65 + lo + i * 4] = f2bf(vv);
  }
  __syncthreads();
#pragma unroll
  for (int i = 0; i < 16; ++i) {
    const int dd = lo + i * 4;
    vt[hb * 64 + (size_t)dd * 1024 + l0 + d] = vtile[dd * 65 + d];
  }
}

// ---------------- flash attention v2: 2-phase pipelined ---------------------
// block = (n, h, 128 q-rows), 256 thr / 4 waves; wave owns 32 q end-to-end.
// R5 analysis: 2580 cy/step measured vs ~1300 of issue work -- the gap was
// staging latency fully exposed by the barrier->stage->barrier pattern. Fix:
// double-buffered K/V, stage(t+1) issued BEFORE compute(t), ONE syncthreads
// per step (its implicit vmcnt(0) drains the prefetch).
// S computed with SWAPPED operands mfma(K,Q): lane holds q=16i+lrow, keys
// 16nt+lgrp*4+r -> 4 consecutive keys pack into one ds_write_b64 (8 stores
// vs 32 scalar), rsum is 2 regs. Redistribution to C-layout rows at the end
// costs 8 shfl. LDS 48KB -> 3 blocks/CU.
__global__ __launch_bounds__(256, 3) void flash_attn(
    const short* __restrict__ qh, const short* __restrict__ kh,
    const short* __restrict__ vt, short* __restrict__ attn,
    float* __restrict__ denw) {
  __shared__ short Ks[2][64 * 64];
  __shared__ short Vs[2][64 * 64];
  __shared__ short Pl[4][32 * 64];      // per-wave private P tiles
  const int bid = blockIdx.x;
  const int n = bid & 7;                // same n -> same XCD (L2 locality)
  const int h = (bid >> 3) & 15;
  const int q0 = (bid >> 7) * 128;
  const int tid = threadIdx.x;
  const int wave = tid >> 6, lane = tid & 63;
  const int lrow = lane & 15, lgrp = lane >> 4;
  const int woff = wave * 32;
  const size_t hb = (size_t)(n * 16 + h) * 65536;

  // Q fragments, in regs for the whole kernel
  bf16x8 aq[2][2];
#pragma unroll
  for (int i = 0; i < 2; ++i)
#pragma unroll
    for (int kk = 0; kk < 2; ++kk)
      aq[i][kk] = *(const bf16x8*)(qh + hb +
          (size_t)(q0 + woff + 16 * i + lrow) * 64 + kk * 32 + lgrp * 8);

  const int srow = tid >> 3;                         // 0..31
  const int schunk = ((tid & 7) ^ (srow & 7)) * 8;   // swizzled source chunk
  const short* Kg = kh + hb + (size_t)srow * 64 + schunk;
  const short* Vg = vt + hb + (size_t)srow * 1024 + schunk;
  short* Pw = &Pl[wave][0];

  f32x4 osum[2][4] = {};
  float rsum[2] = {0.f, 0.f};

  // prologue: stage tile 0 into buf 0
#pragma unroll
  for (int r = 0; r < 2; ++r) {
    async16(Kg + (size_t)(32 * r) * 64, &Ks[0][tid * 8 + r * 2048]);
    async16(Vg + (size_t)(32 * r) * 1024, &Vs[0][tid * 8 + r * 2048]);
  }
  __syncthreads();

  for (int step = 0; step < 16; ++step) {
    const int cur = step & 1;
    if (step < 15) {                    // issue NEXT tile before compute
      const int k1 = (step + 1) * 64;
#pragma unroll
      for (int r = 0; r < 2; ++r) {
        async16(Kg + (size_t)(k1 + 32 * r) * 64, &Ks[cur ^ 1][tid * 8 + r * 2048]);
        async16(Vg + (size_t)(32 * r) * 1024 + k1, &Vs[cur ^ 1][tid * 8 + r * 2048]);
      }
    }
    // ---- S = K @ Q (swapped): lane holds q=16i+lrow, keys 16nt+lgrp*4+r ----
    f32x4 sacc[2][4] = {};
#pragma unroll
    for (int kk = 0; kk < 2; ++kk)
#pragma unroll
      for (int nt = 0; nt < 4; ++nt) {
        const int rb = nt * 16 + lrow;
        const bf16x8 ak = *(const bf16x8*)&Ks[cur][rb * 64 + (((kk * 4 + lgrp) ^ (rb & 7)) * 8)];
#pragma unroll
        for (int i = 0; i < 2; ++i)
          sacc[i][nt] = __builtin_amdgcn_mfma_f32_16x16x32_bf16(ak, aq[i][kk], sacc[i][nt], 0, 0, 0);
      }
    // ---- exp, rowsum, packed P store (4 consecutive keys per b64) ----
#pragma unroll
    for (int i = 0; i < 2; ++i)
#pragma unroll
      for (int nt = 0; nt < 4; ++nt) {
        float e0 = __expf(sacc[i][nt][0]), e1 = __expf(sacc[i][nt][1]);
        float e2 = __expf(sacc[i][nt][2]), e3 = __expf(sacc[i][nt][3]);
        rsum[i] += (e0 + e1) + (e2 + e3);
        short4 pk = make_short4(f2bf(e0), f2bf(e1), f2bf(e2), f2bf(e3));
        const int prow = 16 * i + lrow;
        const int cb = 16 * nt + lgrp * 4;
        *(short4*)&Pw[prow * 64 + ((((cb >> 3) ^ (prow & 7))) << 3) + (cb & 7)] = pk;
      }
    // ---- PV: O += P @ V ----
#pragma unroll
    for (int kk = 0; kk < 2; ++kk) {
      bf16x8 pa[2], bv[4];
#pragma unroll
      for (int i = 0; i < 2; ++i) {
        const int ra = 16 * i + lrow;
        pa[i] = *(const bf16x8*)&Pw[ra * 64 + (((kk * 4 + lgrp) ^ (ra & 7)) * 8)];
      }
#pragma unroll
      for (int j = 0; j < 4; ++j) {
        const int rb = 16 * j + lrow;
        bv[j] = *(const bf16x8*)&Vs[cur][rb * 64 + (((kk * 4 + lgrp) ^ (rb & 7)) * 8)];
      }
#pragma unroll
      for (int i = 0; i < 2; ++i)
#pragma unroll
        for (int j = 0; j < 4; ++j)
          osum[i][j] = __builtin_amdgcn_mfma_f32_16x16x32_bf16(pa[i], bv[j], osum[i][j], 0, 0, 0);
    }
    __syncthreads();                    // drains prefetch vmcnt + buffer swap
  }
  // ---- rowsum reduce across lgrp (key partition); q = 16i+lrow ----
#pragma unroll
  for (int t = 0; t < 2; ++t) {
    rsum[t] += __shfl_xor(rsum[t], 16, 64);
    rsum[t] += __shfl_xor(rsum[t], 32, 64);
  }
  const float invq0 = 1.0f / rsum[0], invq1 = 1.0f / rsum[1];
  if (lgrp == 0) {
    denw[(size_t)(n * 16 + h) * 1024 + q0 + woff + lrow] = invq0;
    denw[(size_t)(n * 16 + h) * 1024 + q0 + woff + 16 + lrow] = invq1;
  }
  // redistribute: C-layout row lgrp*4+r needs inv held at lane lgrp*4+r
  float inv8[8];
#pragma unroll
  for (int r = 0; r < 4; ++r) {
    inv8[r] = __shfl(invq0, lgrp * 4 + r, 64);
    inv8[4 + r] = __shfl(invq1, lgrp * 4 + r, 64);
  }
#pragma unroll
  for (int i = 0; i < 2; ++i)
#pragma unroll
    for (int j = 0; j < 4; ++j)
#pragma unroll
      for (int r = 0; r < 4; ++r) {
        const int row = q0 + woff + 16 * i + lgrp * 4 + r;
        attn[(size_t)(n * 1024 + row) * 1024 + h * 64 + 16 * j + lrow] =
            f2bf(osum[i][j][r] * inv8[i * 4 + r]);
      }
}

// ---------------- out2 v2 = mean over heads of softmax(S), pipelined --------
// block = (n, 128 q-rows, 64-key strip), 256 thr / 4 waves; wave owns 32 q.
// Per head: Q tile (16KB) AND K tile (8KB) staged via async16 (R4 lesson:
// register-loaded global MFMA operands stall), double-buffered across heads,
// ONE barrier per head. denw loads issued at loop top overlap the MFMAs.
// acc over 16 heads in regs, single coalesced out2 write. LDS 48KB -> 3/CU.
__global__ __launch_bounds__(256, 3) void out2_kernel(
    const short* __restrict__ qh, const short* __restrict__ kh,
    const float* __restrict__ denw, float* __restrict__ out2) {
  __shared__ short Qs[2][128 * 64];
  __shared__ short Ks[2][64 * 64];
  const int bid = blockIdx.x;
  const int n = bid & 7;
  const int qt = (bid >> 3) & 7;
  const int kvs = bid >> 6;             // 0..15
  const int q0 = qt * 128, c0 = kvs * 64;
  const int tid = threadIdx.x;
  const int wave = tid >> 6, lane = tid & 63;
  const int lrow = lane & 15, lgrp = lane >> 4;
  const int woff = wave * 32;

  const int srow = tid >> 3;
  const int schunk = ((tid & 7) ^ (srow & 7)) * 8;

  f32x4 acc[2][4] = {};

  // stage head hh's Q+K tiles into buf
  auto stage = [&](int hh, int buf) {
    const size_t hb = (size_t)(n * 16 + hh) * 65536;
#pragma unroll
    for (int r = 0; r < 4; ++r)
      async16(qh + hb + (size_t)(q0 + 32 * r + srow) * 64 + schunk,
              &Qs[buf][tid * 8 + r * 2048]);
#pragma unroll
    for (int r = 0; r < 2; ++r)
      async16(kh + hb + (size_t)(c0 + 32 * r + srow) * 64 + schunk,
              &Ks[buf][tid * 8 + r * 2048]);
  };

  stage(0, 0);
  __syncthreads();
  for (int h = 0; h < 16; ++h) {
    const int cur = h & 1;
    // denw loads first: global, independent -> overlap with MFMAs below
    float invv[8];
#pragma unroll
    for (int i = 0; i < 2; ++i)
#pragma unroll
      for (int r = 0; r < 4; ++r)
        invv[i * 4 + r] =
            denw[(size_t)(n * 16 + h) * 1024 + q0 + woff + 16 * i + lgrp * 4 + r];
    if (h < 15) stage(h + 1, cur ^ 1);
    bf16x8 aq[2][2];
#pragma unroll
    for (int i = 0; i < 2; ++i)
#pragma unroll
      for (int kk = 0; kk < 2; ++kk) {
        const int ra = woff + 16 * i + lrow;
        aq[i][kk] = *(const bf16x8*)&Qs[cur][ra * 64 + (((kk * 4 + lgrp) ^ (ra & 7)) * 8)];
      }
    f32x4 sacc[2][4] = {};
#pragma unroll
    for (int kk = 0; kk < 2; ++kk)
#pragma unroll
      for (int nt = 0; nt < 4; ++nt) {
        const int rb = nt * 16 + lrow;
        const bf16x8 bk = *(const bf16x8*)&Ks[cur][rb * 64 + (((kk * 4 + lgrp) ^ (rb & 7)) * 8)];
#pragma unroll
        for (int i = 0; i < 2; ++i)
          sacc[i][nt] = __builtin_amdgcn_mfma_f32_16x16x32_bf16(aq[i][kk], bk, sacc[i][nt], 0, 0, 0);
      }
#pragma unroll
    for (int i = 0; i < 2; ++i)
#pragma unroll
      for (int nt = 0; nt < 4; ++nt)
#pragma unroll
        for (int r = 0; r < 4; ++r)
          acc[i][nt][r] += __expf(sacc[i][nt][r]) * invv[i * 4 + r];
    __syncthreads();
  }
#pragma unroll
  for (int i = 0; i < 2; ++i)
#pragma unroll
    for (int nt = 0; nt < 4; ++nt)
#pragma unroll
      for (int r = 0; r < 4; ++r) {
        const int row = q0 + woff + 16 * i + lgrp * 4 + r;
        out2[(size_t)(n * 1024 + row) * 1024 + c0 + 16 * nt + lrow] = acc[i][nt][r] * 0.0625f;
      }
}

extern "C" void kernel_launch(void* const* d_in, const int* in_sizes, int n_in,
                              void* d_out, int out_size, void* d_ws, size_t ws_size,
                              hipStream_t stream) {
  const float* x  = (const float*)d_in[0];   // (8,1024,1024)
  const float* Wi = (const float*)d_in[1];   // (3072,1024)
  const float* bi = (const float*)d_in[2];   // (3072,)
  const float* Wo = (const float*)d_in[3];   // (1024,1024)
  const float* bo = (const float*)d_in[4];   // (1024,)
  float* out  = (float*)d_out;                       // (8,1024,1024)
  float* out2 = out + (size_t)8 * 1024 * 1024;       // (8,1024,1024) mean attn

  char* p = (char*)d_ws;
  short* xb  = (short*)p; p += (size_t)8388608 * 2;   // x bf16 (reused as attn later)
  short* wb  = (short*)p; p += (size_t)3145728 * 2;   // W_in bf16
  short* wob = (short*)p; p += (size_t)1048576 * 2;   // W_out bf16
  short* qkv = (short*)p; p += (size_t)8 * 1024 * 3072 * 2;  // 50.3 MB (dead after rope)
  short* qh  = (short*)p; p += (size_t)8388608 * 2;   // (n,h,l,d) bf16, pre-scaled
  short* kh  = (short*)p; p += (size_t)8388608 * 2;   // (n,h,l,d) bf16
  short* vt  = (short*)p; p += (size_t)8388608 * 2;   // (n,h,d,l) bf16
  float* denw = (float*)p; p += (size_t)131072 * 4;   // inv softmax denominators
  short* attn = xb;  // xb dead after gemm_qkv

  convert3<<<2048, 256, 0, stream>>>(x, xb, 8388608 / 4, Wi, wb, 3145728 / 4,
                                     Wo, wob, 1048576 / 4);
  gemm_bt<<<dim3(24, 64), 256, 0, stream>>>(xb, wb, bi, nullptr, qkv, 8192, 3072, 1024);
  rope_kernel<<<dim3(16, 16, 8), 256, 0, stream>>>(qkv, qh, kh, vt);
  flash_attn<<<1024, 256, 0, stream>>>(qh, kh, vt, attn, denw);
  out2_kernel<<<1024, 256, 0, stream>>>(qh, kh, denw, out2);
  gemm_bt<<<dim3(8, 64), 256, 0, stream>>>(attn, wob, bo, out, nullptr, 8192, 1024, 1024);
}

// Round 7
// 288.189 us; speedup vs baseline: 2.0813x; 1.0059x over previous
//
#include <hip/hip_runtime.h>
#include <hip/hip_bf16.h>
#include <math.h>

// Problem constants: N=8, L=1024, D=1024, H=16, hd=64, SCALE=0.125
typedef short bf16x8 __attribute__((ext_vector_type(8)));
typedef float f32x4 __attribute__((ext_vector_type(4)));

__device__ __forceinline__ short f2bf(float f) {
  unsigned u = __float_as_uint(f);
  u += 0x7fffu + ((u >> 16) & 1u);          // RNE
  return (short)(u >> 16);
}
__device__ __forceinline__ float bf2f(short h) {
  return __uint_as_float(((unsigned)(unsigned short)h) << 16);
}

typedef __attribute__((address_space(1))) void glob_void;
typedef __attribute__((address_space(3))) void lds_void;
// async global->LDS, 16B per lane; LDS dest = wave-uniform base + lane*16
__device__ __forceinline__ void async16(const void* g, void* l) {
  __builtin_amdgcn_global_load_lds((glob_void*)(uintptr_t)g,
                                   (lds_void*)(unsigned int)(uintptr_t)l,
                                   16, 0, 0);
}

// ---------------- fp32 -> bf16 conversion of x, W_in, W_out ----------------
__global__ void convert3(const float* __restrict__ a, short* __restrict__ ab, int na4,
                         const float* __restrict__ b, short* __restrict__ bb, int nb4,
                         const float* __restrict__ c, short* __restrict__ cb, int nc4) {
  int tid = blockIdx.x * blockDim.x + threadIdx.x;
  int stride = gridDim.x * blockDim.x;
  for (int i = tid; i < na4; i += stride) {
    float4 v = ((const float4*)a)[i];
    ((short4*)ab)[i] = make_short4(f2bf(v.x), f2bf(v.y), f2bf(v.z), f2bf(v.w));
  }
  for (int i = tid; i < nb4; i += stride) {
    float4 v = ((const float4*)b)[i];
    ((short4*)bb)[i] = make_short4(f2bf(v.x), f2bf(v.y), f2bf(v.z), f2bf(v.w));
  }
  for (int i = tid; i < nc4; i += stride) {
    float4 v = ((const float4*)c)[i];
    ((short4*)cb)[i] = make_short4(f2bf(v.x), f2bf(v.y), f2bf(v.z), f2bf(v.w));
  }
}

// ---------------- m97-style B^T GEMM: C[m][n] = sum_k A[m][k]*B[n][k] + bias[n]
// 1D grid + XCD-chunked swizzle (R6: FETCH=72.8MB vs 23MB of inputs -- same-A
// panel blocks scattered over 8 XCDs refetch panels; staging latency ~HBM,
// fully exposed by the per-step vmcnt(0) drain). swz gives each XCD 8
// consecutive m-panels: A panels stay L2-hot, B (6.3MB) ~fits one L2.
// Requires nwg % 8 == 0 (1536 and 512: both OK).
__global__ __launch_bounds__(256, 2) void gemm_bt(
    const short* __restrict__ A, const short* __restrict__ B,
    const float* __restrict__ bias, float* __restrict__ Cf, short* __restrict__ Cb,
    int M, int N, int K) {
  __shared__ short As[128 * 64];
  __shared__ short Bs[128 * 64];
  const int tid = threadIdx.x;
  const int lane = tid & 63, wave = tid >> 6;
  const int wm = (wave & 1) * 64, wn = (wave >> 1) * 64;
  const int lrow = lane & 15, lgrp = lane >> 4;
  const int xtiles = N >> 7;            // n-tiles per row of the grid
  const int bid = blockIdx.x;
  const int cpx = gridDim.x >> 3;       // chunk per XCD
  const int swz = (bid & 7) * cpx + (bid >> 3);
  const int m0 = (swz / xtiles) * 128, n0 = (swz % xtiles) * 128;
  f32x4 acc[4][4] = {};

  const int srow = tid >> 3;                         // 0..31
  const int schunk = ((tid & 7) ^ (srow & 7)) * 8;   // swizzled source chunk (elems)
  const short* Ag = A + (size_t)(m0 + srow) * K + schunk;
  const short* Bg = B + (size_t)(n0 + srow) * K + schunk;
  short* Al = As + tid * 8;
  short* Bl = Bs + tid * 8;

  for (int k0 = 0; k0 < K; k0 += 64) {
    __syncthreads();
#pragma unroll
    for (int r = 0; r < 4; ++r) {
      async16(Ag + (size_t)(32 * r) * K + k0, Al + r * 2048);
      async16(Bg + (size_t)(32 * r) * K + k0, Bl + r * 2048);
    }
    __syncthreads();
#pragma unroll
    for (int kk = 0; kk < 2; ++kk) {
      bf16x8 af[4], bfr[4];
#pragma unroll
      for (int i = 0; i < 4; ++i) {
        const int ra = wm + i * 16 + lrow;
        af[i] = *(const bf16x8*)&As[ra * 64 + (((kk * 4 + lgrp) ^ (ra & 7)) * 8)];
        const int rb = wn + i * 16 + lrow;
        bfr[i] = *(const bf16x8*)&Bs[rb * 64 + (((kk * 4 + lgrp) ^ (rb & 7)) * 8)];
      }
#pragma unroll
      for (int i = 0; i < 4; ++i)
#pragma unroll
        for (int j = 0; j < 4; ++j)
          acc[i][j] = __builtin_amdgcn_mfma_f32_16x16x32_bf16(af[i], bfr[j], acc[i][j], 0, 0, 0);
    }
  }
#pragma unroll
  for (int j = 0; j < 4; ++j) {
    const int col = n0 + wn + j * 16 + lrow;
    const float bs = bias[col];
#pragma unroll
    for (int i = 0; i < 4; ++i) {
      const int rb = m0 + wm + i * 16 + lgrp * 4;
#pragma unroll
      for (int r = 0; r < 4; ++r) {
        const float v = acc[i][j][r] + bs;
        if (Cf) Cf[(size_t)(rb + r) * N + col] = v;
        else    Cb[(size_t)(rb + r) * N + col] = f2bf(v);
      }
    }
  }
}

// ---------------- RoPE + head-split + V transpose ----------------
__global__ __launch_bounds__(256) void rope_kernel(
    const short* __restrict__ qkv, short* __restrict__ qh,
    short* __restrict__ kh, short* __restrict__ vt) {
  __shared__ short vtile[64 * 65];
  const int l0 = blockIdx.x * 64, h = blockIdx.y, n = blockIdx.z;
  const int tid = threadIdx.x;
  const int d = tid & 63, lo = tid >> 6;
  const int j = d & 31;
  const float invf = exp2f(-0.4152410118609203f * (float)j);  // 10000^(-j/32)
  const float sgn = (d < 32) ? -1.0f : 1.0f;
  const int po = ((d + 32) & 63) - d;  // pair offset for rotate_half
  const size_t hb = (size_t)(n * 16 + h) * 1024;
#pragma unroll
  for (int i = 0; i < 16; ++i) {
    const int l = l0 + lo + i * 4;
    const short* row = qkv + (size_t)(n * 1024 + l) * 3072 + h * 64;
    const float qv = bf2f(row[d]),        qp = bf2f(row[d + po]);
    const float kv = bf2f(row[1024 + d]), kp = bf2f(row[1024 + d + po]);
    const float vv = bf2f(row[2048 + d]);
    float s, c;
    sincosf((float)l * invf, &s, &c);
    qh[(hb + l) * 64 + d] = f2bf((qv * c + sgn * qp * s) * 0.125f);
    kh[(hb + l) * 64 + d] = f2bf(kv * c + sgn * kp * s);
    vtile[d * 65 + lo + i * 4] = f2bf(vv);
  }
  __syncthreads();
#pragma unroll
  for (int i = 0; i < 16; ++i) {
    const int dd = lo + i * 4;
    vt[hb * 64 + (size_t)dd * 1024 + l0 + d] = vtile[dd * 65 + d];
  }
}

// ---------------- flash attention v2: 2-phase pipelined ---------------------
// block = (n, h, 128 q-rows), 256 thr / 4 waves; wave owns 32 q end-to-end.
// Double-buffered K/V, stage(t+1) issued BEFORE compute(t), ONE syncthreads
// per step. S via swapped mfma(K,Q): packed b64 P-stores, 2-reg rsum.
__global__ __launch_bounds__(256, 3) void flash_attn(
    const short* __restrict__ qh, const short* __restrict__ kh,
    const short* __restrict__ vt, short* __restrict__ attn,
    float* __restrict__ denw) {
  __shared__ short Ks[2][64 * 64];
  __shared__ short Vs[2][64 * 64];
  __shared__ short Pl[4][32 * 64];      // per-wave private P tiles
  const int bid = blockIdx.x;
  const int n = bid & 7;                // same n -> same XCD (L2 locality)
  const int h = (bid >> 3) & 15;
  const int q0 = (bid >> 7) * 128;
  const int tid = threadIdx.x;
  const int wave = tid >> 6, lane = tid & 63;
  const int lrow = lane & 15, lgrp = lane >> 4;
  const int woff = wave * 32;
  const size_t hb = (size_t)(n * 16 + h) * 65536;

  // Q fragments, in regs for the whole kernel
  bf16x8 aq[2][2];
#pragma unroll
  for (int i = 0; i < 2; ++i)
#pragma unroll
    for (int kk = 0; kk < 2; ++kk)
      aq[i][kk] = *(const bf16x8*)(qh + hb +
          (size_t)(q0 + woff + 16 * i + lrow) * 64 + kk * 32 + lgrp * 8);

  const int srow = tid >> 3;                         // 0..31
  const int schunk = ((tid & 7) ^ (srow & 7)) * 8;   // swizzled source chunk
  const short* Kg = kh + hb + (size_t)srow * 64 + schunk;
  const short* Vg = vt + hb + (size_t)srow * 1024 + schunk;
  short* Pw = &Pl[wave][0];

  f32x4 osum[2][4] = {};
  float rsum[2] = {0.f, 0.f};

  // prologue: stage tile 0 into buf 0
#pragma unroll
  for (int r = 0; r < 2; ++r) {
    async16(Kg + (size_t)(32 * r) * 64, &Ks[0][tid * 8 + r * 2048]);
    async16(Vg + (size_t)(32 * r) * 1024, &Vs[0][tid * 8 + r * 2048]);
  }
  __syncthreads();

  for (int step = 0; step < 16; ++step) {
    const int cur = step & 1;
    if (step < 15) {                    // issue NEXT tile before compute
      const int k1 = (step + 1) * 64;
#pragma unroll
      for (int r = 0; r < 2; ++r) {
        async16(Kg + (size_t)(k1 + 32 * r) * 64, &Ks[cur ^ 1][tid * 8 + r * 2048]);
        async16(Vg + (size_t)(32 * r) * 1024 + k1, &Vs[cur ^ 1][tid * 8 + r * 2048]);
      }
    }
    // ---- S = K @ Q (swapped): lane holds q=16i+lrow, keys 16nt+lgrp*4+r ----
    f32x4 sacc[2][4] = {};
#pragma unroll
    for (int kk = 0; kk < 2; ++kk)
#pragma unroll
      for (int nt = 0; nt < 4; ++nt) {
        const int rb = nt * 16 + lrow;
        const bf16x8 ak = *(const bf16x8*)&Ks[cur][rb * 64 + (((kk * 4 + lgrp) ^ (rb & 7)) * 8)];
#pragma unroll
        for (int i = 0; i < 2; ++i)
          sacc[i][nt] = __builtin_amdgcn_mfma_f32_16x16x32_bf16(ak, aq[i][kk], sacc[i][nt], 0, 0, 0);
      }
    // ---- exp, rowsum, packed P store (4 consecutive keys per b64) ----
#pragma unroll
    for (int i = 0; i < 2; ++i)
#pragma unroll
      for (int nt = 0; nt < 4; ++nt) {
        float e0 = __expf(sacc[i][nt][0]), e1 = __expf(sacc[i][nt][1]);
        float e2 = __expf(sacc[i][nt][2]), e3 = __expf(sacc[i][nt][3]);
        rsum[i] += (e0 + e1) + (e2 + e3);
        short4 pk = make_short4(f2bf(e0), f2bf(e1), f2bf(e2), f2bf(e3));
        const int prow = 16 * i + lrow;
        const int cb = 16 * nt + lgrp * 4;
        *(short4*)&Pw[prow * 64 + ((((cb >> 3) ^ (prow & 7))) << 3) + (cb & 7)] = pk;
      }
    // ---- PV: O += P @ V ----
#pragma unroll
    for (int kk = 0; kk < 2; ++kk) {
      bf16x8 pa[2], bv[4];
#pragma unroll
      for (int i = 0; i < 2; ++i) {
        const int ra = 16 * i + lrow;
        pa[i] = *(const bf16x8*)&Pw[ra * 64 + (((kk * 4 + lgrp) ^ (ra & 7)) * 8)];
      }
#pragma unroll
      for (int j = 0; j < 4; ++j) {
        const int rb = 16 * j + lrow;
        bv[j] = *(const bf16x8*)&Vs[cur][rb * 64 + (((kk * 4 + lgrp) ^ (rb & 7)) * 8)];
      }
#pragma unroll
      for (int i = 0; i < 2; ++i)
#pragma unroll
        for (int j = 0; j < 4; ++j)
          osum[i][j] = __builtin_amdgcn_mfma_f32_16x16x32_bf16(pa[i], bv[j], osum[i][j], 0, 0, 0);
    }
    __syncthreads();                    // drains prefetch vmcnt + buffer swap
  }
  // ---- rowsum reduce across lgrp (key partition); q = 16i+lrow ----
#pragma unroll
  for (int t = 0; t < 2; ++t) {
    rsum[t] += __shfl_xor(rsum[t], 16, 64);
    rsum[t] += __shfl_xor(rsum[t], 32, 64);
  }
  const float invq0 = 1.0f / rsum[0], invq1 = 1.0f / rsum[1];
  if (lgrp == 0) {
    denw[(size_t)(n * 16 + h) * 1024 + q0 + woff + lrow] = invq0;
    denw[(size_t)(n * 16 + h) * 1024 + q0 + woff + 16 + lrow] = invq1;
  }
  // redistribute: C-layout row lgrp*4+r needs inv held at lane lgrp*4+r
  float inv8[8];
#pragma unroll
  for (int r = 0; r < 4; ++r) {
    inv8[r] = __shfl(invq0, lgrp * 4 + r, 64);
    inv8[4 + r] = __shfl(invq1, lgrp * 4 + r, 64);
  }
#pragma unroll
  for (int i = 0; i < 2; ++i)
#pragma unroll
    for (int j = 0; j < 4; ++j)
#pragma unroll
      for (int r = 0; r < 4; ++r) {
        const int row = q0 + woff + 16 * i + lgrp * 4 + r;
        attn[(size_t)(n * 1024 + row) * 1024 + h * 64 + 16 * j + lrow] =
            f2bf(osum[i][j][r] * inv8[i * 4 + r]);
      }
}

// ---------------- out2 v2 = mean over heads of softmax(S), pipelined --------
// block = (n, 128 q-rows, 64-key strip), 256 thr / 4 waves; wave owns 32 q.
// Q (16KB) + K (8KB) staged via async16, double-buffered across heads,
// ONE barrier per head. acc over 16 heads in regs, single coalesced write.
__global__ __launch_bounds__(256, 3) void out2_kernel(
    const short* __restrict__ qh, const short* __restrict__ kh,
    const float* __restrict__ denw, float* __restrict__ out2) {
  __shared__ short Qs[2][128 * 64];
  __shared__ short Ks[2][64 * 64];
  const int bid = blockIdx.x;
  const int n = bid & 7;
  const int qt = (bid >> 3) & 7;
  const int kvs = bid >> 6;             // 0..15
  const int q0 = qt * 128, c0 = kvs * 64;
  const int tid = threadIdx.x;
  const int wave = tid >> 6, lane = tid & 63;
  const int lrow = lane & 15, lgrp = lane >> 4;
  const int woff = wave * 32;

  const int srow = tid >> 3;
  const int schunk = ((tid & 7) ^ (srow & 7)) * 8;

  f32x4 acc[2][4] = {};

  // stage head hh's Q+K tiles into buf
  auto stage = [&](int hh, int buf) {
    const size_t hb = (size_t)(n * 16 + hh) * 65536;
#pragma unroll
    for (int r = 0; r < 4; ++r)
      async16(qh + hb + (size_t)(q0 + 32 * r + srow) * 64 + schunk,
              &Qs[buf][tid * 8 + r * 2048]);
#pragma unroll
    for (int r = 0; r < 2; ++r)
      async16(kh + hb + (size_t)(c0 + 32 * r + srow) * 64 + schunk,
              &Ks[buf][tid * 8 + r * 2048]);
  };

  stage(0, 0);
  __syncthreads();
  for (int h = 0; h < 16; ++h) {
    const int cur = h & 1;
    // denw loads first: global, independent -> overlap with MFMAs below
    float invv[8];
#pragma unroll
    for (int i = 0; i < 2; ++i)
#pragma unroll
      for (int r = 0; r < 4; ++r)
        invv[i * 4 + r] =
            denw[(size_t)(n * 16 + h) * 1024 + q0 + woff + 16 * i + lgrp * 4 + r];
    if (h < 15) stage(h + 1, cur ^ 1);
    bf16x8 aq[2][2];
#pragma unroll
    for (int i = 0; i < 2; ++i)
#pragma unroll
      for (int kk = 0; kk < 2; ++kk) {
        const int ra = woff + 16 * i + lrow;
        aq[i][kk] = *(const bf16x8*)&Qs[cur][ra * 64 + (((kk * 4 + lgrp) ^ (ra & 7)) * 8)];
      }
    f32x4 sacc[2][4] = {};
#pragma unroll
    for (int kk = 0; kk < 2; ++kk)
#pragma unroll
      for (int nt = 0; nt < 4; ++nt) {
        const int rb = nt * 16 + lrow;
        const bf16x8 bk = *(const bf16x8*)&Ks[cur][rb * 64 + (((kk * 4 + lgrp) ^ (rb & 7)) * 8)];
#pragma unroll
        for (int i = 0; i < 2; ++i)
          sacc[i][nt] = __builtin_amdgcn_mfma_f32_16x16x32_bf16(aq[i][kk], bk, sacc[i][nt], 0, 0, 0);
      }
#pragma unroll
    for (int i = 0; i < 2; ++i)
#pragma unroll
      for (int nt = 0; nt < 4; ++nt)
#pragma unroll
        for (int r = 0; r < 4; ++r)
          acc[i][nt][r] += __expf(sacc[i][nt][r]) * invv[i * 4 + r];
    __syncthreads();
  }
#pragma unroll
  for (int i = 0; i < 2; ++i)
#pragma unroll
    for (int nt = 0; nt < 4; ++nt)
#pragma unroll
      for (int r = 0; r < 4; ++r) {
        const int row = q0 + woff + 16 * i + lgrp * 4 + r;
        out2[(size_t)(n * 1024 + row) * 1024 + c0 + 16 * nt + lrow] = acc[i][nt][r] * 0.0625f;
      }
}

extern "C" void kernel_launch(void* const* d_in, const int* in_sizes, int n_in,
                              void* d_out, int out_size, void* d_ws, size_t ws_size,
                              hipStream_t stream) {
  const float* x  = (const float*)d_in[0];   // (8,1024,1024)
  const float* Wi = (const float*)d_in[1];   // (3072,1024)
  const float* bi = (const float*)d_in[2];   // (3072,)
  const float* Wo = (const float*)d_in[3];   // (1024,1024)
  const float* bo = (const float*)d_in[4];   // (1024,)
  float* out  = (float*)d_out;                       // (8,1024,1024)
  float* out2 = out + (size_t)8 * 1024 * 1024;       // (8,1024,1024) mean attn

  char* p = (char*)d_ws;
  short* xb  = (short*)p; p += (size_t)8388608 * 2;   // x bf16 (reused as attn later)
  short* wb  = (short*)p; p += (size_t)3145728 * 2;   // W_in bf16
  short* wob = (short*)p; p += (size_t)1048576 * 2;   // W_out bf16
  short* qkv = (short*)p; p += (size_t)8 * 1024 * 3072 * 2;  // 50.3 MB (dead after rope)
  short* qh  = (short*)p; p += (size_t)8388608 * 2;   // (n,h,l,d) bf16, pre-scaled
  short* kh  = (short*)p; p += (size_t)8388608 * 2;   // (n,h,l,d) bf16
  short* vt  = (short*)p; p += (size_t)8388608 * 2;   // (n,h,d,l) bf16
  float* denw = (float*)p; p += (size_t)131072 * 4;   // inv softmax denominators
  short* attn = xb;  // xb dead after gemm_qkv

  convert3<<<2048, 256, 0, stream>>>(x, xb, 8388608 / 4, Wi, wb, 3145728 / 4,
                                     Wo, wob, 1048576 / 4);
  gemm_bt<<<1536, 256, 0, stream>>>(xb, wb, bi, nullptr, qkv, 8192, 3072, 1024);
  rope_kernel<<<dim3(16, 16, 8), 256, 0, stream>>>(qkv, qh, kh, vt);
  flash_attn<<<1024, 256, 0, stream>>>(qh, kh, vt, attn, denw);
  out2_kernel<<<1024, 256, 0, stream>>>(qh, kh, denw, out2);
  gemm_bt<<<512, 256, 0, stream>>>(attn, wob, bo, out, nullptr, 8192, 1024, 1024);
}